// Round 1
// baseline (1955.370 us; speedup 1.0000x reference)
//
#include <hip/hip_runtime.h>

// ---------------------------------------------------------------------------
// GCN stack on MI355X. Key restructuring: aggregation S() is linear, so
// S(x@W) == S(x)@W -- we aggregate in 64-dim space for ALL layers, never 640.
// s/w branches share t1 = S(relu(ab+bb)). All fp32 (no fp32 MFMA on CDNA4).
// ---------------------------------------------------------------------------

__global__ void set_val_kernel(float* __restrict__ p, int n, float v) {
    int i = blockIdx.x * blockDim.x + threadIdx.x;
    if (i < n) p[i] = v;
}

__global__ void count_deg_kernel(const int* __restrict__ edges, float* __restrict__ deg, int E) {
    int e = blockIdx.x * blockDim.x + threadIdx.x;
    if (e < E) atomicAdd(&deg[edges[2 * e + 1]], 1.0f);
}

__global__ void rsqrt_inplace_kernel(float* __restrict__ p, int n) {
    int i = blockIdx.x * blockDim.x + threadIdx.x;
    if (i < n) p[i] = rsqrtf(p[i]);
}

// out[i][:] = f(in[i][:]) * dinv[i]^2   (self-loop term; f = optional +bias, relu)
// one thread per float4 -> N*16 threads
__global__ void agg_init_kernel(const float* __restrict__ in, const float* __restrict__ bias,
                                const float* __restrict__ dinv, float* __restrict__ out,
                                int N, int relu) {
    int t = blockIdx.x * blockDim.x + threadIdx.x;
    if (t >= N * 16) return;
    int i  = t >> 4;
    int f4 = (t & 15) << 2;
    float d  = dinv[i];
    float dd = d * d;
    float4 v = *(const float4*)&in[(size_t)i * 64 + f4];
    if (bias) {
        float4 b = *(const float4*)&bias[f4];
        v.x += b.x; v.y += b.y; v.z += b.z; v.w += b.w;
    }
    if (relu) {
        v.x = fmaxf(v.x, 0.f); v.y = fmaxf(v.y, 0.f);
        v.z = fmaxf(v.z, 0.f); v.w = fmaxf(v.w, 0.f);
    }
    v.x *= dd; v.y *= dd; v.z *= dd; v.w *= dd;
    *(float4*)&out[(size_t)i * 64 + f4] = v;
}

// one wave (64 lanes) per edge, grid-stride over edges; lane = feature index
__global__ void agg_scatter_kernel(const float* __restrict__ in, const float* __restrict__ bias,
                                   const int* __restrict__ edges, const float* __restrict__ dinv,
                                   float* __restrict__ out, int E, int relu) {
    int lane = threadIdx.x & 63;
    int wid  = (blockIdx.x * blockDim.x + threadIdx.x) >> 6;
    int nw   = (gridDim.x * blockDim.x) >> 6;
    float b = bias ? bias[lane] : 0.f;
    for (int e = wid; e < E; e += nw) {
        int s = edges[2 * e];
        int d = edges[2 * e + 1];
        float c = dinv[s] * dinv[d];
        float v = in[(size_t)s * 64 + lane];
        if (bias) v += b;
        if (relu) v = fmaxf(v, 0.f);
        atomicAdd(&out[(size_t)d * 64 + lane], v * c);
    }
}

// ---------------------------------------------------------------------------
// fp32 GEMM: C[M,N] = A[M,K] @ B[K,N] (+bias) (optional relu)
// tile 64x64, BK=32, 256 threads, 4x4 micro-tile per thread.
// N, K multiples of 32 here (64 or 640). M guarded.
// ---------------------------------------------------------------------------
template <bool RELU>
__global__ __launch_bounds__(256)
void gemm_kernel(const float* __restrict__ A, const float* __restrict__ B,
                 const float* __restrict__ bias, float* __restrict__ C,
                 int M, int N, int K) {
    __shared__ float sA[64][33];   // [row][k], +1 pad
    __shared__ float sB[32][64];   // [k][col]
    const int tid  = threadIdx.x;
    const int row0 = blockIdx.x * 64;
    const int col0 = blockIdx.y * 64;
    const int tx = tid & 15;       // col group
    const int ty = tid >> 4;       // row group
    const int tx4 = tx << 2, ty4 = ty << 2;

    float acc[4][4] = {};

    for (int kb = 0; kb < K; kb += 32) {
        // A tile 64x32: 512 float4, 2 per thread
#pragma unroll
        for (int l = 0; l < 2; ++l) {
            int f  = tid + l * 256;        // 0..511
            int r  = f >> 3;               // 0..63
            int k4 = (f & 7) << 2;         // 0..28
            float4 v = make_float4(0.f, 0.f, 0.f, 0.f);
            int gr = row0 + r;
            if (gr < M) v = *(const float4*)&A[(size_t)gr * K + kb + k4];
            sA[r][k4 + 0] = v.x; sA[r][k4 + 1] = v.y;
            sA[r][k4 + 2] = v.z; sA[r][k4 + 3] = v.w;
        }
        // B tile 32x64: 512 float4, 2 per thread
#pragma unroll
        for (int l = 0; l < 2; ++l) {
            int f  = tid + l * 256;
            int kr = f >> 4;               // 0..31
            int c4 = (f & 15) << 2;        // 0..60
            *(float4*)&sB[kr][c4] = *(const float4*)&B[(size_t)(kb + kr) * N + col0 + c4];
        }
        __syncthreads();
#pragma unroll
        for (int k = 0; k < 32; ++k) {
            float a0 = sA[ty4 + 0][k];
            float a1 = sA[ty4 + 1][k];
            float a2 = sA[ty4 + 2][k];
            float a3 = sA[ty4 + 3][k];
            float4 b = *(const float4*)&sB[k][tx4];
            acc[0][0] = fmaf(a0, b.x, acc[0][0]); acc[0][1] = fmaf(a0, b.y, acc[0][1]);
            acc[0][2] = fmaf(a0, b.z, acc[0][2]); acc[0][3] = fmaf(a0, b.w, acc[0][3]);
            acc[1][0] = fmaf(a1, b.x, acc[1][0]); acc[1][1] = fmaf(a1, b.y, acc[1][1]);
            acc[1][2] = fmaf(a1, b.z, acc[1][2]); acc[1][3] = fmaf(a1, b.w, acc[1][3]);
            acc[2][0] = fmaf(a2, b.x, acc[2][0]); acc[2][1] = fmaf(a2, b.y, acc[2][1]);
            acc[2][2] = fmaf(a2, b.z, acc[2][2]); acc[2][3] = fmaf(a2, b.w, acc[2][3]);
            acc[3][0] = fmaf(a3, b.x, acc[3][0]); acc[3][1] = fmaf(a3, b.y, acc[3][1]);
            acc[3][2] = fmaf(a3, b.z, acc[3][2]); acc[3][3] = fmaf(a3, b.w, acc[3][3]);
        }
        __syncthreads();
    }

    float4 bv = make_float4(0.f, 0.f, 0.f, 0.f);
    if (bias) bv = *(const float4*)&bias[col0 + tx4];
#pragma unroll
    for (int i = 0; i < 4; ++i) {
        int gr = row0 + ty4 + i;
        if (gr < M) {
            float4 v;
            v.x = acc[i][0] + bv.x; v.y = acc[i][1] + bv.y;
            v.z = acc[i][2] + bv.z; v.w = acc[i][3] + bv.w;
            if (RELU) {
                v.x = fmaxf(v.x, 0.f); v.y = fmaxf(v.y, 0.f);
                v.z = fmaxf(v.z, 0.f); v.w = fmaxf(v.w, 0.f);
            }
            *(float4*)&C[(size_t)gr * N + col0 + tx4] = v;
        }
    }
}

extern "C" void kernel_launch(void* const* d_in, const int* in_sizes, int n_in,
                              void* d_out, int out_size, void* d_ws, size_t ws_size,
                              hipStream_t stream) {
    const float* x     = (const float*)d_in[0];
    const int*   edges = (const int*)d_in[1];
    const float* Wb    = (const float*)d_in[2];
    const float* bb    = (const float*)d_in[3];
    const float* Ws1   = (const float*)d_in[4];
    const float* bs1   = (const float*)d_in[5];
    const float* Ws2   = (const float*)d_in[6];
    const float* bs2   = (const float*)d_in[7];
    const float* Ww1   = (const float*)d_in[8];
    const float* bw1   = (const float*)d_in[9];
    const float* Ww2   = (const float*)d_in[10];
    const float* bw2   = (const float*)d_in[11];

    const int N = in_sizes[0] / 640;   // 50000
    const int E = in_sizes[1] / 2;     // 1600000

    float* out_xs = (float*)d_out;
    float* out_xw = out_xs + (size_t)N * 640;

    float* ws   = (float*)d_ws;
    float* dinv = ws;                        // N floats (deg computed in place)
    size_t nf   = (size_t)N * 64;            // 3.2M floats per 64-dim buffer
    float* B0   = ws + 50048;                // hb, later t2
    float* B1   = B0 + nf;                   // ab, later xw1
    float* B2   = B1 + nf;                   // t1 (shared by s/w branches)
    float* B3   = B2 + nf;                   // xs1, later t3

    const int nBlkN   = (N + 255) / 256;
    const int nBlkE   = (E + 255) / 256;
    const int nBlkIni = (N * 16 + 255) / 256;
    const int rowT    = (N + 63) / 64;
    const dim3 blk(256);

    // --- degree / dinv ---
    set_val_kernel<<<nBlkN, blk, 0, stream>>>(dinv, N, 1.0f);
    count_deg_kernel<<<nBlkE, blk, 0, stream>>>(edges, dinv, E);
    rsqrt_inplace_kernel<<<nBlkN, blk, 0, stream>>>(dinv, N);

    // --- G1: hb = x @ Wb   (bias applied post-aggregation) ---
    gemm_kernel<false><<<dim3(rowT, 1), blk, 0, stream>>>(x, Wb, nullptr, B0, N, 64, 640);

    // --- A1: ab = S(hb) ---
    agg_init_kernel<<<nBlkIni, blk, 0, stream>>>(B0, nullptr, dinv, B1, N, 0);
    agg_scatter_kernel<<<4096, blk, 0, stream>>>(B0, nullptr, edges, dinv, B1, E, 0);

    // --- A2: t1 = S(relu(ab + bb)) = S(xb) ---
    agg_init_kernel<<<nBlkIni, blk, 0, stream>>>(B1, bb, dinv, B2, N, 1);
    agg_scatter_kernel<<<4096, blk, 0, stream>>>(B1, bb, edges, dinv, B2, E, 1);

    // --- G2: xs1 = relu(t1 @ Ws1 + bs1) ---
    gemm_kernel<true><<<dim3(rowT, 1), blk, 0, stream>>>(B2, Ws1, bs1, B3, N, 64, 64);

    // --- A3: t2 = S(xs1) ---
    agg_init_kernel<<<nBlkIni, blk, 0, stream>>>(B3, nullptr, dinv, B0, N, 0);
    agg_scatter_kernel<<<4096, blk, 0, stream>>>(B3, nullptr, edges, dinv, B0, E, 0);

    // --- G3: xs = relu(t2 @ Ws2 + bs2) -> d_out ---
    gemm_kernel<true><<<dim3(rowT, 10), blk, 0, stream>>>(B0, Ws2, bs2, out_xs, N, 640, 64);

    // --- G4: xw1 = relu(t1 @ Ww1 + bw1) ---
    gemm_kernel<true><<<dim3(rowT, 1), blk, 0, stream>>>(B2, Ww1, bw1, B1, N, 64, 64);

    // --- A4: t3 = S(xw1) ---
    agg_init_kernel<<<nBlkIni, blk, 0, stream>>>(B1, nullptr, dinv, B3, N, 0);
    agg_scatter_kernel<<<4096, blk, 0, stream>>>(B1, nullptr, edges, dinv, B3, E, 0);

    // --- G5: xw = relu(t3 @ Ww2 + bw2) -> d_out ---
    gemm_kernel<true><<<dim3(rowT, 10), blk, 0, stream>>>(B3, Ww2, bw2, out_xw, N, 640, 64);
}

// Round 2
// 1053.849 us; speedup vs baseline: 1.8555x; 1.8555x over previous
//
#include <hip/hip_runtime.h>

// ---------------------------------------------------------------------------
// GCN stack on MI355X.
// R0: S(x@W) == S(x)@W -> aggregate in 64-dim space always; share t1.
// R1: replace atomic scatter (400 MB write-through per pass) with
//     counting-sort CSR + register-accumulating gather (one wave per dst
//     node, lane = feature). Self-term + bias + relu fused into the gather.
// ---------------------------------------------------------------------------

__global__ void zero_int_kernel(int* __restrict__ p, int n) {
    int i = blockIdx.x * blockDim.x + threadIdx.x;
    if (i < n) p[i] = 0;
}

__global__ void hist_kernel(const int* __restrict__ edges, int* __restrict__ cnt, int E) {
    int e = blockIdx.x * blockDim.x + threadIdx.x;
    if (e < E) atomicAdd(&cnt[edges[2 * e + 1]], 1);
}

// per-block inclusive scan (1024 elems) -> exclusive partial + blocksum; also dinv
__global__ __launch_bounds__(1024)
void scan_block_kernel(const int* __restrict__ cnt, int* __restrict__ excl,
                       int* __restrict__ blocksum, float* __restrict__ dinv, int N) {
    __shared__ int s[1024];
    int tid = threadIdx.x;
    int i = blockIdx.x * 1024 + tid;
    int v = (i < N) ? cnt[i] : 0;
    if (i < N) dinv[i] = rsqrtf((float)v + 1.0f);
    s[tid] = v;
    __syncthreads();
    for (int off = 1; off < 1024; off <<= 1) {
        int t = (tid >= off) ? s[tid - off] : 0;
        __syncthreads();
        s[tid] += t;
        __syncthreads();
    }
    if (i < N) excl[i] = s[tid] - v;
    if (tid == 1023) blocksum[blockIdx.x] = s[1023];
}

__global__ void scan_partials_kernel(int* __restrict__ blocksum, int nb) {
    if (blockIdx.x == 0 && threadIdx.x == 0) {
        int run = 0;
        for (int i = 0; i < nb; ++i) { int v = blocksum[i]; blocksum[i] = run; run += v; }
    }
}

__global__ void scan_finalize_kernel(int* __restrict__ row_start, const int* __restrict__ blocksum,
                                     int* __restrict__ cursor, int N, int E) {
    int i = blockIdx.x * blockDim.x + threadIdx.x;
    if (i < N) {
        int v = row_start[i] + blocksum[i >> 10];
        row_start[i] = v;
        cursor[i] = v;
    }
    if (i == N) row_start[N] = E;
}

__global__ void build_csr_kernel(const int* __restrict__ edges, int* __restrict__ cursor,
                                 int* __restrict__ csr_src, int E) {
    int e = blockIdx.x * blockDim.x + threadIdx.x;
    if (e < E) {
        int s = edges[2 * e], d = edges[2 * e + 1];
        int pos = atomicAdd(&cursor[d], 1);
        csr_src[pos] = s;
    }
}

// out[d] = f(in[d])*dinv[d]^2 + sum_{s in nbrs(d)} f(in[s])*dinv[s]*dinv[d]
// one wave per dst node, lane = feature (64 == wave size). No atomics.
template <bool BIAS, bool RELU>
__global__ __launch_bounds__(256)
void agg_gather_kernel(const float* __restrict__ in, const float* __restrict__ bias,
                       const int* __restrict__ row_start, const int* __restrict__ csr_src,
                       const float* __restrict__ dinv, float* __restrict__ out, int N) {
    int lane = threadIdx.x & 63;
    int wid  = (blockIdx.x * blockDim.x + threadIdx.x) >> 6;
    int nw   = (gridDim.x * blockDim.x) >> 6;
    float b = BIAS ? bias[lane] : 0.f;
    for (int d = wid; d < N; d += nw) {
        float dv = dinv[d];
        float v = in[(size_t)d * 64 + lane];
        if (BIAS) v += b;
        if (RELU) v = fmaxf(v, 0.f);
        float acc0 = v * dv * dv;
        float acc1 = 0.f;
        int e   = row_start[d];
        int end = row_start[d + 1];
        // 2-way unrolled: two loads in flight, two independent acc chains
        for (; e + 1 < end; e += 2) {
            int s0 = csr_src[e], s1 = csr_src[e + 1];
            float c0 = dinv[s0] * dv, c1 = dinv[s1] * dv;
            float u0 = in[(size_t)s0 * 64 + lane];
            float u1 = in[(size_t)s1 * 64 + lane];
            if (BIAS) { u0 += b; u1 += b; }
            if (RELU) { u0 = fmaxf(u0, 0.f); u1 = fmaxf(u1, 0.f); }
            acc0 = fmaf(u0, c0, acc0);
            acc1 = fmaf(u1, c1, acc1);
        }
        if (e < end) {
            int s0 = csr_src[e];
            float c0 = dinv[s0] * dv;
            float u0 = in[(size_t)s0 * 64 + lane];
            if (BIAS) u0 += b;
            if (RELU) u0 = fmaxf(u0, 0.f);
            acc0 = fmaf(u0, c0, acc0);
        }
        out[(size_t)d * 64 + lane] = acc0 + acc1;
    }
}

// ---------------------------------------------------------------------------
// fp32 GEMM: C[M,N] = A[M,K] @ B[K,N] (+bias) (optional relu)
// tile 64x64, BK=32, 256 threads, 4x4 micro-tile per thread.
// ---------------------------------------------------------------------------
template <bool RELU>
__global__ __launch_bounds__(256)
void gemm_kernel(const float* __restrict__ A, const float* __restrict__ B,
                 const float* __restrict__ bias, float* __restrict__ C,
                 int M, int N, int K) {
    __shared__ float sA[64][33];
    __shared__ float sB[32][64];
    const int tid  = threadIdx.x;
    const int row0 = blockIdx.x * 64;
    const int col0 = blockIdx.y * 64;
    const int tx = tid & 15;
    const int ty = tid >> 4;
    const int tx4 = tx << 2, ty4 = ty << 2;

    float acc[4][4] = {};

    for (int kb = 0; kb < K; kb += 32) {
#pragma unroll
        for (int l = 0; l < 2; ++l) {
            int f  = tid + l * 256;
            int r  = f >> 3;
            int k4 = (f & 7) << 2;
            float4 v = make_float4(0.f, 0.f, 0.f, 0.f);
            int gr = row0 + r;
            if (gr < M) v = *(const float4*)&A[(size_t)gr * K + kb + k4];
            sA[r][k4 + 0] = v.x; sA[r][k4 + 1] = v.y;
            sA[r][k4 + 2] = v.z; sA[r][k4 + 3] = v.w;
        }
#pragma unroll
        for (int l = 0; l < 2; ++l) {
            int f  = tid + l * 256;
            int kr = f >> 4;
            int c4 = (f & 15) << 2;
            *(float4*)&sB[kr][c4] = *(const float4*)&B[(size_t)(kb + kr) * N + col0 + c4];
        }
        __syncthreads();
#pragma unroll
        for (int k = 0; k < 32; ++k) {
            float a0 = sA[ty4 + 0][k];
            float a1 = sA[ty4 + 1][k];
            float a2 = sA[ty4 + 2][k];
            float a3 = sA[ty4 + 3][k];
            float4 b = *(const float4*)&sB[k][tx4];
            acc[0][0] = fmaf(a0, b.x, acc[0][0]); acc[0][1] = fmaf(a0, b.y, acc[0][1]);
            acc[0][2] = fmaf(a0, b.z, acc[0][2]); acc[0][3] = fmaf(a0, b.w, acc[0][3]);
            acc[1][0] = fmaf(a1, b.x, acc[1][0]); acc[1][1] = fmaf(a1, b.y, acc[1][1]);
            acc[1][2] = fmaf(a1, b.z, acc[1][2]); acc[1][3] = fmaf(a1, b.w, acc[1][3]);
            acc[2][0] = fmaf(a2, b.x, acc[2][0]); acc[2][1] = fmaf(a2, b.y, acc[2][1]);
            acc[2][2] = fmaf(a2, b.z, acc[2][2]); acc[2][3] = fmaf(a2, b.w, acc[2][3]);
            acc[3][0] = fmaf(a3, b.x, acc[3][0]); acc[3][1] = fmaf(a3, b.y, acc[3][1]);
            acc[3][2] = fmaf(a3, b.z, acc[3][2]); acc[3][3] = fmaf(a3, b.w, acc[3][3]);
        }
        __syncthreads();
    }

    float4 bv = make_float4(0.f, 0.f, 0.f, 0.f);
    if (bias) bv = *(const float4*)&bias[col0 + tx4];
#pragma unroll
    for (int i = 0; i < 4; ++i) {
        int gr = row0 + ty4 + i;
        if (gr < M) {
            float4 v;
            v.x = acc[i][0] + bv.x; v.y = acc[i][1] + bv.y;
            v.z = acc[i][2] + bv.z; v.w = acc[i][3] + bv.w;
            if (RELU) {
                v.x = fmaxf(v.x, 0.f); v.y = fmaxf(v.y, 0.f);
                v.z = fmaxf(v.z, 0.f); v.w = fmaxf(v.w, 0.f);
            }
            *(float4*)&C[(size_t)gr * N + col0 + tx4] = v;
        }
    }
}

extern "C" void kernel_launch(void* const* d_in, const int* in_sizes, int n_in,
                              void* d_out, int out_size, void* d_ws, size_t ws_size,
                              hipStream_t stream) {
    const float* x     = (const float*)d_in[0];
    const int*   edges = (const int*)d_in[1];
    const float* Wb    = (const float*)d_in[2];
    const float* bb    = (const float*)d_in[3];
    const float* Ws1   = (const float*)d_in[4];
    const float* bs1   = (const float*)d_in[5];
    const float* Ws2   = (const float*)d_in[6];
    const float* bs2   = (const float*)d_in[7];
    const float* Ww1   = (const float*)d_in[8];
    const float* bw1   = (const float*)d_in[9];
    const float* Ww2   = (const float*)d_in[10];
    const float* bw2   = (const float*)d_in[11];

    const int N = in_sizes[0] / 640;   // 50000
    const int E = in_sizes[1] / 2;     // 1600000

    float* out_xs = (float*)d_out;
    float* out_xw = out_xs + (size_t)N * 640;

    // workspace layout (all 256B-aligned): small arrays, CSR, 3 rotating bufs
    const size_t NP = ((size_t)N + 64) & ~63ULL;   // padded count
    char* w = (char*)d_ws;
    float* dinv      = (float*)w;              w += NP * 4;
    int*   cnt       = (int*)w;                w += NP * 4;
    int*   row_start = (int*)w;                w += (NP + 64) * 4;
    int*   cursor    = (int*)w;                w += NP * 4;
    int*   csr_src   = (int*)w;                w += ((size_t)E + 64) * 4;
    size_t nf = (size_t)N * 64;
    float* B0 = (float*)w;                     w += nf * 4;
    float* B1 = (float*)w;                     w += nf * 4;
    float* B2 = (float*)w;                     w += nf * 4;

    const dim3 blk(256);
    const int nBlkN   = (N + 255) / 256;
    const int nBlkN1  = (N + 256) / 256;       // covers i == N
    const int nBlkE   = (E + 255) / 256;
    const int nScanB  = (N + 1023) / 1024;
    const int rowT    = (N + 63) / 64;
    const int gatherB = (N + 3) / 4;           // 4 waves per block, 1 wave/node

    // --- CSR build + dinv ---
    zero_int_kernel<<<nBlkN, blk, 0, stream>>>(cnt, N);
    hist_kernel<<<nBlkE, blk, 0, stream>>>(edges, cnt, E);
    scan_block_kernel<<<nScanB, 1024, 0, stream>>>(cnt, row_start, cursor /*tmp blocksum*/, dinv, N);
    scan_partials_kernel<<<1, 64, 0, stream>>>(cursor, nScanB);
    scan_finalize_kernel<<<nBlkN1, blk, 0, stream>>>(row_start, cursor, cnt /*reuse as cursor*/, N, E);
    build_csr_kernel<<<nBlkE, blk, 0, stream>>>(edges, cnt, csr_src, E);

    // --- G1: hb = x @ Wb (bias folded into A2's read transform) ---
    gemm_kernel<false><<<dim3(rowT, 1), blk, 0, stream>>>(x, Wb, nullptr, B0, N, 64, 640);

    // --- A1: ab = S(hb) ---
    agg_gather_kernel<false, false><<<gatherB, blk, 0, stream>>>(B0, nullptr, row_start, csr_src, dinv, B1, N);

    // --- A2: t1 = S(relu(ab + bb)) ---
    agg_gather_kernel<true, true><<<gatherB, blk, 0, stream>>>(B1, bb, row_start, csr_src, dinv, B2, N);

    // --- s branch: G2 -> A3 -> G3 ---
    gemm_kernel<true><<<dim3(rowT, 1), blk, 0, stream>>>(B2, Ws1, bs1, B0, N, 64, 64);
    agg_gather_kernel<false, false><<<gatherB, blk, 0, stream>>>(B0, nullptr, row_start, csr_src, dinv, B1, N);
    gemm_kernel<true><<<dim3(rowT, 10), blk, 0, stream>>>(B1, Ws2, bs2, out_xs, N, 640, 64);

    // --- w branch: G4 -> A4 -> G5 ---
    gemm_kernel<true><<<dim3(rowT, 1), blk, 0, stream>>>(B2, Ww1, bw1, B0, N, 64, 64);
    agg_gather_kernel<false, false><<<gatherB, blk, 0, stream>>>(B0, nullptr, row_start, csr_src, dinv, B1, N);
    gemm_kernel<true><<<dim3(rowT, 10), blk, 0, stream>>>(B1, Ww2, bw2, out_xw, N, 640, 64);
}